// Round 14
// baseline (423.920 us; speedup 1.0000x reference)
//
#include <hip/hip_runtime.h>
#include <hip/hip_bf16.h>
#include <hip/hip_fp16.h>

#define FEAT 128

typedef __attribute__((ext_vector_type(8))) short short8;
typedef __attribute__((ext_vector_type(4))) float f32x4;

static __device__ __forceinline__ unsigned short f2bf(float f) {
    unsigned int u = __float_as_uint(f);
    unsigned int r = (u + 0x7fffu + ((u >> 16) & 1u)) >> 16;
    return (unsigned short)r;
}
static __device__ __forceinline__ float bf2f(unsigned short b) {
    return __uint_as_float(((unsigned int)b) << 16);
}

// ---- CSR build -------------------------------------------------------------
// STRIDED CSR (r13): edges live permanently in fixed b*BCAP bucket regions of
// tmp; bucket_fill3 sorts each bucket IN PLACE and emits per-node
// indse={start,end}. Pipeline: memset(bcur) -> scatter(+wprep) -> fill3 ->
// [gemm, agg] x3.
// ROUND-14 = MEASUREMENT ROUND: each agg dispatch is split into two
// half-range dispatches (~31 us each) so that any hidden kernel >31 us
// (scatter/fill3/gemm) surfaces in the rocprof top-5. agg math unchanged.
// POST-MORTEM LEDGER (do not retry):
//  r8  feature-sliced gather: FETCH 195->86 MB but 94 us (divergence).
//  r9  edge-centric LDS-atomic accumulate: 1075 us (LDS bank conflicts).
//  r11 nontemporal loads/stores: 83 us, FETCH +13 MB (nt bypasses L2). NO NT.
//  r13 CSR streamlining: ~0 gain — launch gaps/small kernels are not the cost.
// The r4 agg structure is the measured optimum: 61.9-63.8 us across six
// variants = pattern ceiling (~4 TB/s) for random 256 B gathers.

#define BKT_SHIFT 7
#define BKT_G 128
#define MAX_NB 1024
#define BCAP 3072
#define SC_T 32
#define SC_EPB (256 * SC_T)   // 8192 edges per block

__global__ __launch_bounds__(256)
void scatter_wprep_kernel(const int* __restrict__ src, const int* __restrict__ dst,
                          int* __restrict__ bcur, unsigned int* __restrict__ tmp,
                          int E, int NB, int EB,
                          const float* __restrict__ W1, const float* __restrict__ W2,
                          const float* __restrict__ W3, unsigned short* __restrict__ wth,
                          unsigned short* __restrict__ wtl) {
    if ((int)blockIdx.x >= EB) {
        // weight prep: 192 blocks x 256 = 3 * 16384 items
        int idx = ((int)blockIdx.x - EB) * 256 + threadIdx.x;
        int l = idx >> 14, t = idx & 16383;
        int nn = t >> 7, kk = t & 127;
        const float* W = (l == 0) ? W1 : (l == 1) ? W2 : W3;
        float v = W[kk * 128 + nn];
        unsigned short h = f2bf(v);
        wth[idx] = h;
        wtl[idx] = f2bf(v - bf2f(h));
        return;
    }

    __shared__ int hist[MAX_NB];
    const int tid = threadIdx.x;
    const int ebase = blockIdx.x * SC_EPB;

    for (int i = tid; i < NB; i += 256) hist[i] = 0;
    __syncthreads();

    unsigned int pk[SC_T];    // packed (src,dst_local)
    unsigned int meta[SC_T];  // (bucket<<16) | local_rank ; 0xFFFFFFFF = invalid
    #pragma unroll
    for (int j = 0; j < SC_T; ++j) {
        int e = ebase + j * 256 + tid;
        if (e < E) {
            int s = src[e], d = dst[e];
            int b = d >> BKT_SHIFT;
            pk[j] = ((unsigned int)s << BKT_SHIFT) | (unsigned int)(d & (BKT_G - 1));
            int r = atomicAdd(&hist[b], 1);
            meta[j] = ((unsigned int)b << 16) | (unsigned int)r;
        } else {
            meta[j] = 0xFFFFFFFFu;
        }
    }
    __syncthreads();

    // one global atomic per (block,bucket); bcur holds COUNTS (memset 0);
    // the fixed b*BCAP region base is added here.
    for (int b = tid; b < NB; b += 256) {
        int c = hist[b];
        if (c > 0) hist[b] = b * BCAP + atomicAdd(&bcur[b], c);
    }
    __syncthreads();

    #pragma unroll
    for (int j = 0; j < SC_T; ++j) {
        if (meta[j] != 0xFFFFFFFFu) {
            int b = meta[j] >> 16;
            int r = (int)(meta[j] & 0xFFFFu);
            tmp[hist[b] + r] = pk[j];
        }
    }
}

// block b: single pass bucket -> LDS (+hist), scan 128 counts, emit dinv and
// indse={start,end} (absolute into tmp), scatter sorted src back IN PLACE.
__global__ __launch_bounds__(256)
void bucket_fill3_kernel(unsigned int* __restrict__ tmp, const int* __restrict__ bcur,
                         int2* __restrict__ indse, float* __restrict__ dinv, int n) {
    __shared__ unsigned int eb[BCAP];
    __shared__ int cnt[BKT_G];
    __shared__ int cur[BKT_G];
    __shared__ int wtot;
    const int tid = threadIdx.x;
    const int b = blockIdx.x;
    const int nodebase = b * BKT_G;
    const int scnt = bcur[b];
    unsigned int* tp = tmp + (size_t)b * BCAP;

    if (tid < BKT_G) cnt[tid] = 0;
    __syncthreads();
    for (int e = tid; e < scnt; e += 256) {
        unsigned int v = tp[e];
        eb[e] = v;
        atomicAdd(&cnt[v & (BKT_G - 1)], 1);
    }
    __syncthreads();

    int c = 0, x = 0;
    if (tid < BKT_G) {
        int lane = tid & 63;
        c = cnt[tid];
        x = c;
        #pragma unroll
        for (int off = 1; off < 64; off <<= 1) {
            int y = __shfl_up(x, off);
            if (lane >= off) x += y;
        }
    }
    if (tid == 63) wtot = x;   // wave0 inclusive total
    __syncthreads();
    if (tid < BKT_G) {
        int excl = x - c + ((tid >= 64) ? wtot : 0);
        int node = nodebase + tid;
        if (node < n) {
            dinv[node]  = rsqrtf((float)(c + 1));
            int s0 = b * BCAP + excl;
            indse[node] = make_int2(s0, s0 + c);
        }
        cur[tid] = excl;   // local offset within bucket
    }
    __syncthreads();
    for (int e = tid; e < scnt; e += 256) {
        unsigned int v = eb[e];
        int pos = atomicAdd(&cur[v & (BKT_G - 1)], 1);
        tp[pos] = v >> BKT_SHIFT;   // sorted src index (source is LDS: no hazard)
    }
}

// ---- GEMM (split-bf16 MFMA, B staged in LDS): hs = (in @ W) * dinv, fp16 out
// 128-row M-tile, 512 threads (8 waves), 69.6 KB LDS -> 2 blocks/CU = 16
// waves/CU. Layer 1 reads f32 x directly and splits to bf16 hi/lo in-register.
// hs writes stay CACHED (agg re-reads hs ~17x).

template <bool F32IN>
__global__ __launch_bounds__(512)
void gemm_mfma(const float* __restrict__ xf, const unsigned short* __restrict__ xh,
               const unsigned short* __restrict__ xl,
               const unsigned short* __restrict__ wth, const unsigned short* __restrict__ wtl,
               const float* __restrict__ dinv, __half* __restrict__ hs, int n) {
    __shared__ unsigned short bh[128][136];
    __shared__ unsigned short bl[128][136];

    const int tid = threadIdx.x;
    const int wave = tid >> 6, lane = tid & 63;
    const int rowbase = blockIdx.x * 128 + wave * 16;
    const int m = lane & 15, kg = lane >> 4;

    // stage B: 512 threads, 128 B each. plane p = tid>>8 (0=hi,1=lo)
    {
        const int p = tid >> 8, t = tid & 255;
        const int n0 = t >> 1, kk0 = (t & 1) * 64;
        const unsigned short* g = (p ? wtl : wth) + (size_t)n0 * FEAT + kk0;
        unsigned short (*dstp)[136] = p ? bl : bh;
        #pragma unroll
        for (int j = 0; j < 8; ++j)
            *(short8*)&dstp[n0][kk0 + j * 8] = *(const short8*)(g + j * 8);
    }

    // A fragments (loaded while staging is in flight)
    int arow = rowbase + m;
    if (arow > n - 1) arow = n - 1;          // clamp; clamped rows never stored
    short8 avh[4], avl[4];
    if constexpr (F32IN) {
        const float* ap = xf + (size_t)arow * FEAT + kg * 8;
        #pragma unroll
        for (int s = 0; s < 4; ++s) {
            float4 f0 = *(const float4*)(ap + s * 32);
            float4 f1 = *(const float4*)(ap + s * 32 + 4);
            float fv[8] = {f0.x, f0.y, f0.z, f0.w, f1.x, f1.y, f1.z, f1.w};
            short8 h, l;
            #pragma unroll
            for (int k = 0; k < 8; ++k) {
                unsigned short hb = f2bf(fv[k]);
                h[k] = (short)hb;
                l[k] = (short)f2bf(fv[k] - bf2f(hb));
            }
            avh[s] = h; avl[s] = l;
        }
    } else {
        const size_t aoff = (size_t)arow * FEAT + kg * 8;
        #pragma unroll
        for (int s = 0; s < 4; ++s) {
            avh[s] = *(const short8*)(xh + aoff + s * 32);
            avl[s] = *(const short8*)(xl + aoff + s * 32);
        }
    }

    __syncthreads();

    f32x4 acc[8];
    #pragma unroll
    for (int t = 0; t < 8; ++t) acc[t] = (f32x4){0.f, 0.f, 0.f, 0.f};

    #pragma unroll 2
    for (int t = 0; t < 8; ++t) {
        #pragma unroll
        for (int s = 0; s < 4; ++s) {
            short8 bvh = *(const short8*)&bh[t * 16 + m][s * 32 + kg * 8];
            short8 bvl = *(const short8*)&bl[t * 16 + m][s * 32 + kg * 8];
            acc[t] = __builtin_amdgcn_mfma_f32_16x16x32_bf16(avh[s], bvh, acc[t], 0, 0, 0);
            acc[t] = __builtin_amdgcn_mfma_f32_16x16x32_bf16(avh[s], bvl, acc[t], 0, 0, 0);
            acc[t] = __builtin_amdgcn_mfma_f32_16x16x32_bf16(avl[s], bvh, acc[t], 0, 0, 0);
        }
    }

    const int col = lane & 15, rb = (lane >> 4) * 4;
    #pragma unroll
    for (int r = 0; r < 4; ++r) {
        int row = rowbase + rb + r;
        if (row < n) {
            float d = dinv[row];
            __half* hrow = hs + (size_t)row * FEAT;
            #pragma unroll
            for (int t = 0; t < 8; ++t)
                hrow[t * 16 + col] = __float2half(acc[t][r] * d);
        }
    }
}

// ---- aggregation: out = act( dinv[i]*(hs[i] + sum hs[src]) + b ) -----------
// r4 structure — the six-variant-verified optimum: one node per wave, scalar-
// pipe indices via readfirstlane, 8 coalesced 256 B gathers in flight, 4
// register accumulators. r14: processes node range [n0,n1) so each layer's
// agg splits into two ~31 us dispatches (measurement aid; math identical).

__global__ __launch_bounds__(256)
void agg_kernel(const __half* __restrict__ hs, const int2* __restrict__ indse,
                const int* __restrict__ ssrc, const float* __restrict__ dinv,
                const float* __restrict__ bias, float* __restrict__ outf,
                unsigned short* __restrict__ outh, unsigned short* __restrict__ outl,
                int n0, int n1, int do_relu) {
    int wid = threadIdx.x >> 6, lane = threadIdx.x & 63;
    int node = n0 + blockIdx.x * 4 + wid;
    if (node >= n1) return;
    node = __builtin_amdgcn_readfirstlane(node);

    const __half2* hs2 = (const __half2*)hs;
    float d = dinv[node];
    float2 bv = ((const float2*)bias)[lane];
    float2 a0 = __half22float2(hs2[(size_t)node * 64 + lane]);  // self-loop term
    float2 a1 = {0.f, 0.f}, a2 = {0.f, 0.f}, a3 = {0.f, 0.f};

    int2 se = indse[node];
    int start = __builtin_amdgcn_readfirstlane(se.x);
    int end   = __builtin_amdgcn_readfirstlane(se.y);
    const int* sp = ssrc + start;
    int cnt = end - start;

    int j = 0;
    for (; j + 8 <= cnt; j += 8) {
        int s0 = __builtin_amdgcn_readfirstlane(sp[j + 0]);
        int s1 = __builtin_amdgcn_readfirstlane(sp[j + 1]);
        int s2 = __builtin_amdgcn_readfirstlane(sp[j + 2]);
        int s3 = __builtin_amdgcn_readfirstlane(sp[j + 3]);
        int s4 = __builtin_amdgcn_readfirstlane(sp[j + 4]);
        int s5 = __builtin_amdgcn_readfirstlane(sp[j + 5]);
        int s6 = __builtin_amdgcn_readfirstlane(sp[j + 6]);
        int s7 = __builtin_amdgcn_readfirstlane(sp[j + 7]);
        float2 v0 = __half22float2(hs2[(size_t)s0 * 64 + lane]);
        float2 v1 = __half22float2(hs2[(size_t)s1 * 64 + lane]);
        float2 v2 = __half22float2(hs2[(size_t)s2 * 64 + lane]);
        float2 v3 = __half22float2(hs2[(size_t)s3 * 64 + lane]);
        float2 v4 = __half22float2(hs2[(size_t)s4 * 64 + lane]);
        float2 v5 = __half22float2(hs2[(size_t)s5 * 64 + lane]);
        float2 v6 = __half22float2(hs2[(size_t)s6 * 64 + lane]);
        float2 v7 = __half22float2(hs2[(size_t)s7 * 64 + lane]);
        a0.x += v0.x; a0.y += v0.y;
        a1.x += v1.x; a1.y += v1.y;
        a2.x += v2.x; a2.y += v2.y;
        a3.x += v3.x; a3.y += v3.y;
        a0.x += v4.x; a0.y += v4.y;
        a1.x += v5.x; a1.y += v5.y;
        a2.x += v6.x; a2.y += v6.y;
        a3.x += v7.x; a3.y += v7.y;
    }
    for (; j + 2 <= cnt; j += 2) {
        int s0 = __builtin_amdgcn_readfirstlane(sp[j + 0]);
        int s1 = __builtin_amdgcn_readfirstlane(sp[j + 1]);
        float2 v0 = __half22float2(hs2[(size_t)s0 * 64 + lane]);
        float2 v1 = __half22float2(hs2[(size_t)s1 * 64 + lane]);
        a0.x += v0.x; a0.y += v0.y;
        a1.x += v1.x; a1.y += v1.y;
    }
    if (j < cnt) {
        int s = __builtin_amdgcn_readfirstlane(sp[j]);
        float2 v = __half22float2(hs2[(size_t)s * 64 + lane]);
        a2.x += v.x; a2.y += v.y;
    }

    float ox = ((a0.x + a1.x) + (a2.x + a3.x)) * d + bv.x;
    float oy = ((a0.y + a1.y) + (a2.y + a3.y)) * d + bv.y;
    if (do_relu) { ox = fmaxf(ox, 0.f); oy = fmaxf(oy, 0.f); }

    if (outf) {
        float2 o; o.x = ox; o.y = oy;
        ((float2*)outf)[(size_t)node * 64 + lane] = o;
    } else {
        ushort2 h, l;
        h.x = f2bf(ox); l.x = f2bf(ox - bf2f(h.x));
        h.y = f2bf(oy); l.y = f2bf(oy - bf2f(h.y));
        ((ushort2*)outh)[(size_t)node * 64 + lane] = h;
        ((ushort2*)outl)[(size_t)node * 64 + lane] = l;
    }
}

// ---- launch ----------------------------------------------------------------

static inline size_t align256(size_t x) { return (x + 255) & ~(size_t)255; }

extern "C" void kernel_launch(void* const* d_in, const int* in_sizes, int n_in,
                              void* d_out, int out_size, void* d_ws, size_t ws_size,
                              hipStream_t stream) {
    const float* x  = (const float*)d_in[0];
    const int*   ei = (const int*)d_in[1];
    const float* W1 = (const float*)d_in[2];
    const float* b1 = (const float*)d_in[3];
    const float* W2 = (const float*)d_in[4];
    const float* b2 = (const float*)d_in[5];
    const float* W3 = (const float*)d_in[6];
    const float* b3 = (const float*)d_in[7];

    int n = in_sizes[0] / FEAT;      // 100000
    int E = in_sizes[1] / 2;         // 1600000
    const int* src = ei;
    const int* dst = ei + E;
    int NB = (n + BKT_G - 1) >> BKT_SHIFT;   // 782 buckets (n <= 131072 assumed)
    int EB = (E + SC_EPB - 1) / SC_EPB;      // 196 scatter blocks

    // workspace carve-up (~36.6 MB)
    char* w = (char*)d_ws;
    int2* indse  = (int2*)w;                   w += align256((size_t)n * 8);
    int* bcur    = (int*)w;                    w += align256((size_t)MAX_NB * 4);
    float* dinv  = (float*)w;                  w += align256((size_t)n * 4);
    unsigned int* tmp = (unsigned int*)w;      w += align256((size_t)NB * BCAP * 4);
    __half* hs   = (__half*)w;                 w += align256((size_t)n * FEAT * 2);
    unsigned short* wth = (unsigned short*)w;  w += align256((size_t)3 * 16384 * 2);
    unsigned short* wtl = (unsigned short*)w;  w += align256((size_t)3 * 16384 * 2);

    // split activations live in d_out (exactly n*FEAT*4 bytes = two bf16 planes)
    unsigned short* xh = (unsigned short*)d_out;
    unsigned short* xl = xh + (size_t)n * FEAT;

    hipMemsetAsync(bcur, 0, (size_t)NB * 4, stream);   // bcur = per-bucket counts
    scatter_wprep_kernel<<<EB + 192, 256, 0, stream>>>(src, dst, bcur, tmp, E, NB, EB,
                                                       W1, W2, W3, wth, wtl);
    bucket_fill3_kernel<<<NB, 256, 0, stream>>>(tmp, bcur, indse, dinv, n);

    const int gemm_grid = (n + 127) / 128;
    const int nh = (n + 1) / 2;                // agg half-range split point
    for (int L = 0; L < 3; ++L) {
        const float* bb = (L == 0) ? b1 : (L == 1) ? b2 : b3;

        if (L == 0) {
            gemm_mfma<true><<<gemm_grid, 512, 0, stream>>>(x, nullptr, nullptr,
                                                           wth, wtl, dinv, hs, n);
        } else {
            gemm_mfma<false><<<gemm_grid, 512, 0, stream>>>(nullptr, xh, xl,
                                                            wth + (size_t)L * 16384,
                                                            wtl + (size_t)L * 16384,
                                                            dinv, hs, n);
        }
        float* of = (L == 2) ? (float*)d_out : nullptr;
        unsigned short* oh = (L == 2) ? nullptr : xh;
        unsigned short* ol = (L == 2) ? nullptr : xl;
        int relu = (L < 2) ? 1 : 0;
        agg_kernel<<<(nh + 3) / 4, 256, 0, stream>>>(hs, indse, (const int*)tmp, dinv, bb,
                                                     of, oh, ol, 0, nh, relu);
        agg_kernel<<<(n - nh + 3) / 4, 256, 0, stream>>>(hs, indse, (const int*)tmp, dinv, bb,
                                                         of, oh, ol, nh, n, relu);
    }
}

// Round 15
// 401.477 us; speedup vs baseline: 1.0559x; 1.0559x over previous
//
#include <hip/hip_runtime.h>
#include <hip/hip_bf16.h>
#include <hip/hip_fp16.h>

#define FEAT 128

typedef __attribute__((ext_vector_type(8))) short short8;
typedef __attribute__((ext_vector_type(4))) float f32x4;

static __device__ __forceinline__ unsigned short f2bf(float f) {
    unsigned int u = __float_as_uint(f);
    unsigned int r = (u + 0x7fffu + ((u >> 16) & 1u)) >> 16;
    return (unsigned short)r;
}
static __device__ __forceinline__ float bf2f(unsigned short b) {
    return __uint_as_float(((unsigned int)b) << 16);
}

// ---- CSR build -------------------------------------------------------------
// STRIDED CSR (r13): edges live permanently in fixed b*BCAP bucket regions of
// tmp; bucket_fill3 sorts each bucket IN PLACE and emits per-node
// indse={start,end}. Pipeline: memset(bcur) -> scatter(+wprep) -> fill3 ->
// [gemm, agg] x3  (9 dispatches).
// POST-MORTEM LEDGER (do not retry):
//  r8  feature-sliced gather: FETCH 195->86 MB but 94 us (divergence).
//  r9  edge-centric LDS-atomic accumulate: 1075 us (LDS bank conflicts).
//  r11 nontemporal loads/stores: 83 us, FETCH +13 MB (nt bypasses L2). NO NT.
//  r13 CSR streamlining: ~0 gain — launch gaps/small kernels are not the cost.
//  r14 MEASUREMENT: split agg halves exposed top-5 -> every non-agg kernel
//      is < 41 us (harness's 42-us poison fills are the new vis threshold);
//      split cost +20 us (~7 us/dispatch) -> reverted here.
// The r4 agg structure is the measured optimum: 61.9-63.8 us across six
// variants = pattern ceiling (~4 TB/s) for random 256 B gathers.

#define BKT_SHIFT 7
#define BKT_G 128
#define MAX_NB 1024
#define BCAP 3072
#define SC_T 32
#define SC_EPB (256 * SC_T)   // 8192 edges per block

__global__ __launch_bounds__(256)
void scatter_wprep_kernel(const int* __restrict__ src, const int* __restrict__ dst,
                          int* __restrict__ bcur, unsigned int* __restrict__ tmp,
                          int E, int NB, int EB,
                          const float* __restrict__ W1, const float* __restrict__ W2,
                          const float* __restrict__ W3, unsigned short* __restrict__ wth,
                          unsigned short* __restrict__ wtl) {
    if ((int)blockIdx.x >= EB) {
        // weight prep: 192 blocks x 256 = 3 * 16384 items
        int idx = ((int)blockIdx.x - EB) * 256 + threadIdx.x;
        int l = idx >> 14, t = idx & 16383;
        int nn = t >> 7, kk = t & 127;
        const float* W = (l == 0) ? W1 : (l == 1) ? W2 : W3;
        float v = W[kk * 128 + nn];
        unsigned short h = f2bf(v);
        wth[idx] = h;
        wtl[idx] = f2bf(v - bf2f(h));
        return;
    }

    __shared__ int hist[MAX_NB];
    const int tid = threadIdx.x;
    const int ebase = blockIdx.x * SC_EPB;

    for (int i = tid; i < NB; i += 256) hist[i] = 0;
    __syncthreads();

    unsigned int pk[SC_T];    // packed (src,dst_local)
    unsigned int meta[SC_T];  // (bucket<<16) | local_rank ; 0xFFFFFFFF = invalid
    #pragma unroll
    for (int j = 0; j < SC_T; ++j) {
        int e = ebase + j * 256 + tid;
        if (e < E) {
            int s = src[e], d = dst[e];
            int b = d >> BKT_SHIFT;
            pk[j] = ((unsigned int)s << BKT_SHIFT) | (unsigned int)(d & (BKT_G - 1));
            int r = atomicAdd(&hist[b], 1);
            meta[j] = ((unsigned int)b << 16) | (unsigned int)r;
        } else {
            meta[j] = 0xFFFFFFFFu;
        }
    }
    __syncthreads();

    // one global atomic per (block,bucket); bcur holds COUNTS (memset 0);
    // the fixed b*BCAP region base is added here.
    for (int b = tid; b < NB; b += 256) {
        int c = hist[b];
        if (c > 0) hist[b] = b * BCAP + atomicAdd(&bcur[b], c);
    }
    __syncthreads();

    #pragma unroll
    for (int j = 0; j < SC_T; ++j) {
        if (meta[j] != 0xFFFFFFFFu) {
            int b = meta[j] >> 16;
            int r = (int)(meta[j] & 0xFFFFu);
            tmp[hist[b] + r] = pk[j];
        }
    }
}

// block b: single pass bucket -> LDS (+hist), scan 128 counts, emit dinv and
// indse={start,end} (absolute into tmp), scatter sorted src back IN PLACE.
__global__ __launch_bounds__(256)
void bucket_fill3_kernel(unsigned int* __restrict__ tmp, const int* __restrict__ bcur,
                         int2* __restrict__ indse, float* __restrict__ dinv, int n) {
    __shared__ unsigned int eb[BCAP];
    __shared__ int cnt[BKT_G];
    __shared__ int cur[BKT_G];
    __shared__ int wtot;
    const int tid = threadIdx.x;
    const int b = blockIdx.x;
    const int nodebase = b * BKT_G;
    const int scnt = bcur[b];
    unsigned int* tp = tmp + (size_t)b * BCAP;

    if (tid < BKT_G) cnt[tid] = 0;
    __syncthreads();
    for (int e = tid; e < scnt; e += 256) {
        unsigned int v = tp[e];
        eb[e] = v;
        atomicAdd(&cnt[v & (BKT_G - 1)], 1);
    }
    __syncthreads();

    int c = 0, x = 0;
    if (tid < BKT_G) {
        int lane = tid & 63;
        c = cnt[tid];
        x = c;
        #pragma unroll
        for (int off = 1; off < 64; off <<= 1) {
            int y = __shfl_up(x, off);
            if (lane >= off) x += y;
        }
    }
    if (tid == 63) wtot = x;   // wave0 inclusive total
    __syncthreads();
    if (tid < BKT_G) {
        int excl = x - c + ((tid >= 64) ? wtot : 0);
        int node = nodebase + tid;
        if (node < n) {
            dinv[node]  = rsqrtf((float)(c + 1));
            int s0 = b * BCAP + excl;
            indse[node] = make_int2(s0, s0 + c);
        }
        cur[tid] = excl;   // local offset within bucket
    }
    __syncthreads();
    for (int e = tid; e < scnt; e += 256) {
        unsigned int v = eb[e];
        int pos = atomicAdd(&cur[v & (BKT_G - 1)], 1);
        tp[pos] = v >> BKT_SHIFT;   // sorted src index (source is LDS: no hazard)
    }
}

// ---- GEMM (split-bf16 MFMA, B staged in LDS): hs = (in @ W) * dinv, fp16 out
// 128-row M-tile, 512 threads (8 waves), 69.6 KB LDS -> 2 blocks/CU = 16
// waves/CU. Layer 1 reads f32 x directly and splits to bf16 hi/lo in-register.
// r15: epilogue repacks acc through LDS (reusing the dead bh buffer) so hs
// stores are contiguous 16 B/lane (short8) instead of 32 scattered 2 B
// stores per lane. Same acc*dinv -> fp16 math: bit-identical output.

template <bool F32IN>
__global__ __launch_bounds__(512)
void gemm_mfma(const float* __restrict__ xf, const unsigned short* __restrict__ xh,
               const unsigned short* __restrict__ xl,
               const unsigned short* __restrict__ wth, const unsigned short* __restrict__ wtl,
               const float* __restrict__ dinv, __half* __restrict__ hs, int n) {
    __shared__ unsigned short bh[128][136];
    __shared__ unsigned short bl[128][136];

    const int tid = threadIdx.x;
    const int wave = tid >> 6, lane = tid & 63;
    const int rowbase = blockIdx.x * 128 + wave * 16;
    const int m = lane & 15, kg = lane >> 4;

    // stage B: 512 threads, 128 B each. plane p = tid>>8 (0=hi,1=lo)
    {
        const int p = tid >> 8, t = tid & 255;
        const int n0 = t >> 1, kk0 = (t & 1) * 64;
        const unsigned short* g = (p ? wtl : wth) + (size_t)n0 * FEAT + kk0;
        unsigned short (*dstp)[136] = p ? bl : bh;
        #pragma unroll
        for (int j = 0; j < 8; ++j)
            *(short8*)&dstp[n0][kk0 + j * 8] = *(const short8*)(g + j * 8);
    }

    // A fragments (loaded while staging is in flight)
    int arow = rowbase + m;
    if (arow > n - 1) arow = n - 1;          // clamp; clamped rows never stored
    short8 avh[4], avl[4];
    if constexpr (F32IN) {
        const float* ap = xf + (size_t)arow * FEAT + kg * 8;
        #pragma unroll
        for (int s = 0; s < 4; ++s) {
            float4 f0 = *(const float4*)(ap + s * 32);
            float4 f1 = *(const float4*)(ap + s * 32 + 4);
            float fv[8] = {f0.x, f0.y, f0.z, f0.w, f1.x, f1.y, f1.z, f1.w};
            short8 h, l;
            #pragma unroll
            for (int k = 0; k < 8; ++k) {
                unsigned short hb = f2bf(fv[k]);
                h[k] = (short)hb;
                l[k] = (short)f2bf(fv[k] - bf2f(hb));
            }
            avh[s] = h; avl[s] = l;
        }
    } else {
        const size_t aoff = (size_t)arow * FEAT + kg * 8;
        #pragma unroll
        for (int s = 0; s < 4; ++s) {
            avh[s] = *(const short8*)(xh + aoff + s * 32);
            avl[s] = *(const short8*)(xl + aoff + s * 32);
        }
    }

    __syncthreads();

    f32x4 acc[8];
    #pragma unroll
    for (int t = 0; t < 8; ++t) acc[t] = (f32x4){0.f, 0.f, 0.f, 0.f};

    #pragma unroll 2
    for (int t = 0; t < 8; ++t) {
        #pragma unroll
        for (int s = 0; s < 4; ++s) {
            short8 bvh = *(const short8*)&bh[t * 16 + m][s * 32 + kg * 8];
            short8 bvl = *(const short8*)&bl[t * 16 + m][s * 32 + kg * 8];
            acc[t] = __builtin_amdgcn_mfma_f32_16x16x32_bf16(avh[s], bvh, acc[t], 0, 0, 0);
            acc[t] = __builtin_amdgcn_mfma_f32_16x16x32_bf16(avh[s], bvl, acc[t], 0, 0, 0);
            acc[t] = __builtin_amdgcn_mfma_f32_16x16x32_bf16(avl[s], bvh, acc[t], 0, 0, 0);
        }
    }

    // ---- epilogue (r15): LDS repack -> coalesced 16 B stores ----------------
    __syncthreads();   // all waves done reading bh/bl; reuse bh as out buffer
    {
        unsigned short (*outb)[136] = bh;
        const int col = lane & 15, rb = (lane >> 4) * 4;
        #pragma unroll
        for (int r = 0; r < 4; ++r) {
            int lrow = wave * 16 + rb + r;
            int row = rowbase + rb + r;
            float d = dinv[(row < n) ? row : (n - 1)];
            #pragma unroll
            for (int t = 0; t < 8; ++t)
                outb[lrow][t * 16 + col] =
                    __half_as_ushort(__float2half(acc[t][r] * d));
        }
        __syncthreads();
        const int base = blockIdx.x * 128;
        #pragma unroll
        for (int k = 0; k < 4; ++k) {
            int cid = k * 512 + tid;          // 2048 chunks of 8 halfs
            int lrow = cid >> 4, c8 = cid & 15;
            int row = base + lrow;
            if (row < n)
                *(short8*)(hs + (size_t)row * FEAT + c8 * 8) =
                    *(const short8*)&outb[lrow][c8 * 8];
        }
    }
}

// ---- aggregation: out = act( dinv[i]*(hs[i] + sum hs[src]) + b ) -----------
// r4 structure — the six-variant-verified optimum: one node per wave, scalar-
// pipe indices via readfirstlane, 8 coalesced 256 B gathers in flight, 4
// register accumulators. Single dispatch per layer (r14 split reverted).

__global__ __launch_bounds__(256)
void agg_kernel(const __half* __restrict__ hs, const int2* __restrict__ indse,
                const int* __restrict__ ssrc, const float* __restrict__ dinv,
                const float* __restrict__ bias, float* __restrict__ outf,
                unsigned short* __restrict__ outh, unsigned short* __restrict__ outl,
                int n, int do_relu) {
    int wid = threadIdx.x >> 6, lane = threadIdx.x & 63;
    int node = blockIdx.x * 4 + wid;
    if (node >= n) return;
    node = __builtin_amdgcn_readfirstlane(node);

    const __half2* hs2 = (const __half2*)hs;
    float d = dinv[node];
    float2 bv = ((const float2*)bias)[lane];
    float2 a0 = __half22float2(hs2[(size_t)node * 64 + lane]);  // self-loop term
    float2 a1 = {0.f, 0.f}, a2 = {0.f, 0.f}, a3 = {0.f, 0.f};

    int2 se = indse[node];
    int start = __builtin_amdgcn_readfirstlane(se.x);
    int end   = __builtin_amdgcn_readfirstlane(se.y);
    const int* sp = ssrc + start;
    int cnt = end - start;

    int j = 0;
    for (; j + 8 <= cnt; j += 8) {
        int s0 = __builtin_amdgcn_readfirstlane(sp[j + 0]);
        int s1 = __builtin_amdgcn_readfirstlane(sp[j + 1]);
        int s2 = __builtin_amdgcn_readfirstlane(sp[j + 2]);
        int s3 = __builtin_amdgcn_readfirstlane(sp[j + 3]);
        int s4 = __builtin_amdgcn_readfirstlane(sp[j + 4]);
        int s5 = __builtin_amdgcn_readfirstlane(sp[j + 5]);
        int s6 = __builtin_amdgcn_readfirstlane(sp[j + 6]);
        int s7 = __builtin_amdgcn_readfirstlane(sp[j + 7]);
        float2 v0 = __half22float2(hs2[(size_t)s0 * 64 + lane]);
        float2 v1 = __half22float2(hs2[(size_t)s1 * 64 + lane]);
        float2 v2 = __half22float2(hs2[(size_t)s2 * 64 + lane]);
        float2 v3 = __half22float2(hs2[(size_t)s3 * 64 + lane]);
        float2 v4 = __half22float2(hs2[(size_t)s4 * 64 + lane]);
        float2 v5 = __half22float2(hs2[(size_t)s5 * 64 + lane]);
        float2 v6 = __half22float2(hs2[(size_t)s6 * 64 + lane]);
        float2 v7 = __half22float2(hs2[(size_t)s7 * 64 + lane]);
        a0.x += v0.x; a0.y += v0.y;
        a1.x += v1.x; a1.y += v1.y;
        a2.x += v2.x; a2.y += v2.y;
        a3.x += v3.x; a3.y += v3.y;
        a0.x += v4.x; a0.y += v4.y;
        a1.x += v5.x; a1.y += v5.y;
        a2.x += v6.x; a2.y += v6.y;
        a3.x += v7.x; a3.y += v7.y;
    }
    for (; j + 2 <= cnt; j += 2) {
        int s0 = __builtin_amdgcn_readfirstlane(sp[j + 0]);
        int s1 = __builtin_amdgcn_readfirstlane(sp[j + 1]);
        float2 v0 = __half22float2(hs2[(size_t)s0 * 64 + lane]);
        float2 v1 = __half22float2(hs2[(size_t)s1 * 64 + lane]);
        a0.x += v0.x; a0.y += v0.y;
        a1.x += v1.x; a1.y += v1.y;
    }
    if (j < cnt) {
        int s = __builtin_amdgcn_readfirstlane(sp[j]);
        float2 v = __half22float2(hs2[(size_t)s * 64 + lane]);
        a2.x += v.x; a2.y += v.y;
    }

    float ox = ((a0.x + a1.x) + (a2.x + a3.x)) * d + bv.x;
    float oy = ((a0.y + a1.y) + (a2.y + a3.y)) * d + bv.y;
    if (do_relu) { ox = fmaxf(ox, 0.f); oy = fmaxf(oy, 0.f); }

    if (outf) {
        float2 o; o.x = ox; o.y = oy;
        ((float2*)outf)[(size_t)node * 64 + lane] = o;
    } else {
        ushort2 h, l;
        h.x = f2bf(ox); l.x = f2bf(ox - bf2f(h.x));
        h.y = f2bf(oy); l.y = f2bf(oy - bf2f(h.y));
        ((ushort2*)outh)[(size_t)node * 64 + lane] = h;
        ((ushort2*)outl)[(size_t)node * 64 + lane] = l;
    }
}

// ---- launch ----------------------------------------------------------------

static inline size_t align256(size_t x) { return (x + 255) & ~(size_t)255; }

extern "C" void kernel_launch(void* const* d_in, const int* in_sizes, int n_in,
                              void* d_out, int out_size, void* d_ws, size_t ws_size,
                              hipStream_t stream) {
    const float* x  = (const float*)d_in[0];
    const int*   ei = (const int*)d_in[1];
    const float* W1 = (const float*)d_in[2];
    const float* b1 = (const float*)d_in[3];
    const float* W2 = (const float*)d_in[4];
    const float* b2 = (const float*)d_in[5];
    const float* W3 = (const float*)d_in[6];
    const float* b3 = (const float*)d_in[7];

    int n = in_sizes[0] / FEAT;      // 100000
    int E = in_sizes[1] / 2;         // 1600000
    const int* src = ei;
    const int* dst = ei + E;
    int NB = (n + BKT_G - 1) >> BKT_SHIFT;   // 782 buckets (n <= 131072 assumed)
    int EB = (E + SC_EPB - 1) / SC_EPB;      // 196 scatter blocks

    // workspace carve-up (~36.6 MB)
    char* w = (char*)d_ws;
    int2* indse  = (int2*)w;                   w += align256((size_t)n * 8);
    int* bcur    = (int*)w;                    w += align256((size_t)MAX_NB * 4);
    float* dinv  = (float*)w;                  w += align256((size_t)n * 4);
    unsigned int* tmp = (unsigned int*)w;      w += align256((size_t)NB * BCAP * 4);
    __half* hs   = (__half*)w;                 w += align256((size_t)n * FEAT * 2);
    unsigned short* wth = (unsigned short*)w;  w += align256((size_t)3 * 16384 * 2);
    unsigned short* wtl = (unsigned short*)w;  w += align256((size_t)3 * 16384 * 2);

    // split activations live in d_out (exactly n*FEAT*4 bytes = two bf16 planes)
    unsigned short* xh = (unsigned short*)d_out;
    unsigned short* xl = xh + (size_t)n * FEAT;

    hipMemsetAsync(bcur, 0, (size_t)NB * 4, stream);   // bcur = per-bucket counts
    scatter_wprep_kernel<<<EB + 192, 256, 0, stream>>>(src, dst, bcur, tmp, E, NB, EB,
                                                       W1, W2, W3, wth, wtl);
    bucket_fill3_kernel<<<NB, 256, 0, stream>>>(tmp, bcur, indse, dinv, n);

    const int gemm_grid = (n + 127) / 128;
    for (int L = 0; L < 3; ++L) {
        const float* bb = (L == 0) ? b1 : (L == 1) ? b2 : b3;

        if (L == 0) {
            gemm_mfma<true><<<gemm_grid, 512, 0, stream>>>(x, nullptr, nullptr,
                                                           wth, wtl, dinv, hs, n);
        } else {
            gemm_mfma<false><<<gemm_grid, 512, 0, stream>>>(nullptr, xh, xl,
                                                            wth + (size_t)L * 16384,
                                                            wtl + (size_t)L * 16384,
                                                            dinv, hs, n);
        }
        if (L < 2) {
            agg_kernel<<<(n + 3) / 4, 256, 0, stream>>>(hs, indse, (const int*)tmp, dinv, bb,
                                                        nullptr, xh, xl, n, 1);
        } else {
            agg_kernel<<<(n + 3) / 4, 256, 0, stream>>>(hs, indse, (const int*)tmp, dinv, bb,
                                                        (float*)d_out, nullptr, nullptr, n, 0);
        }
    }
}